// Round 2
// baseline (1021.538 us; speedup 1.0000x reference)
//
#include <hip/hip_runtime.h>
#include <math.h>

#define B_ 2
#define S_ 2048
#define H_ 4
#define D_ 64
#define W_ 64
#define A_ 65          // window length W+1
#define STRIDE 68      // LDS row stride in floats: 16B-aligned rows, odd 16B-group stride
#define SCALE_ 0.125f  // 1/sqrt(64)

__global__ __launch_bounds__(256)
void tsattn_kernel(const float* __restrict__ q,
                   const float* __restrict__ k1,
                   const float* __restrict__ k2,
                   const float* __restrict__ v1,
                   const float* __restrict__ v2,
                   float* __restrict__ out)
{
    const int s = blockIdx.x;
    const int h = blockIdx.y;
    const int b = blockIdx.z;
    const int tid = threadIdx.x;

    __shared__ float bufA[A_][STRIDE];   // p = q*k1w, later v1w
    __shared__ float bufB[A_][STRIDE];   // k2w,       later v2w
    __shared__ float wbuf[A_][A_ + 1];   // exp(scores), masked
    __shared__ float red[256];

    const int qbase = ((b * S_ + s) * H_ + h) * D_;   // row base for this (b,s,h)
    const int amin  = (s >= W_) ? 0 : (W_ - s);       // first valid window slot

    // ---- Phase 1a: stage p and k2w into LDS (float4, coalesced) ----
    for (int idx = tid; idx < A_ * 16; idx += 256) {
        int a  = idx >> 4;       // window slot 0..64
        int d4 = idx & 15;       // float4 index within D
        int jc = s - W_ + a; if (jc < 0) jc = 0;     // clamped position
        int off = ((b * S_ + jc) * H_ + h) * D_ + 4 * d4;
        float4 k1v = *(const float4*)(k1 + off);
        float4 k2v = *(const float4*)(k2 + off);
        float4 qv  = *(const float4*)(q + qbase + 4 * d4);
        float4 pv;
        pv.x = qv.x * k1v.x; pv.y = qv.y * k1v.y;
        pv.z = qv.z * k1v.z; pv.w = qv.w * k1v.w;
        *(float4*)&bufA[a][4 * d4] = pv;
        *(float4*)&bufB[a][4 * d4] = k2v;
    }
    __syncthreads();

    // ---- Phase 1b: scores -> exp -> wbuf, accumulate denom partial ----
    float dsum = 0.f;
    for (int idx = tid; idx < A_ * A_; idx += 256) {
        int a = idx / A_;
        int c = idx - a * A_;
        float wv = 0.f;
        if (a >= amin && c >= amin) {
            const float4* pa = (const float4*)&bufA[a][0];
            const float4* kc = (const float4*)&bufB[c][0];
            float sc = 0.f;
            #pragma unroll
            for (int d4 = 0; d4 < 16; ++d4) {
                float4 x = pa[d4];
                float4 y = kc[d4];
                sc += x.x * y.x + x.y * y.y + x.z * y.z + x.w * y.w;
            }
            wv = __expf(sc * SCALE_);
            dsum += wv;
        }
        wbuf[a][c] = wv;
    }
    red[tid] = dsum;
    __syncthreads();   // all wbuf writes + bufA/bufB reads done

    // ---- Phase 2a: reload v1w/v2w over the same buffers ----
    for (int idx = tid; idx < A_ * 16; idx += 256) {
        int a  = idx >> 4;
        int d4 = idx & 15;
        int jc = s - W_ + a; if (jc < 0) jc = 0;
        int off = ((b * S_ + jc) * H_ + h) * D_ + 4 * d4;
        *(float4*)&bufA[a][4 * d4] = *(const float4*)(v1 + off);
        *(float4*)&bufB[a][4 * d4] = *(const float4*)(v2 + off);
    }

    // ---- denom tree reduce (barriers also fence the v loads) ----
    for (int offr = 128; offr > 0; offr >>= 1) {
        if (tid < offr) red[tid] += red[tid + offr];
        __syncthreads();
    }
    const float denom = red[0] + 1e-8f;
    __syncthreads();   // red reused below

    // ---- Phase 2b: num[d] = sum_a v1[a,d] * (sum_c w[a,c] * v2[c,d]) ----
    const int d   = tid & 63;
    const int grp = tid >> 6;    // 0..3, strided rows of a
    float acc = 0.f;
    for (int a = grp; a < A_; a += 4) {
        float tmp = 0.f;
        #pragma unroll 4
        for (int c = 0; c < A_; ++c) {
            tmp += wbuf[a][c] * bufB[c][d];   // w broadcast, v2 conflict-free
        }
        acc += tmp * bufA[a][d];
    }
    red[tid] = acc;
    __syncthreads();
    if (tid < 64) {
        float num = red[tid] + red[tid + 64] + red[tid + 128] + red[tid + 192];
        out[qbase + tid] = num / denom;
    }
}

extern "C" void kernel_launch(void* const* d_in, const int* in_sizes, int n_in,
                              void* d_out, int out_size, void* d_ws, size_t ws_size,
                              hipStream_t stream) {
    const float* q  = (const float*)d_in[0];
    const float* k1 = (const float*)d_in[1];
    const float* k2 = (const float*)d_in[2];
    const float* v1 = (const float*)d_in[3];
    const float* v2 = (const float*)d_in[4];
    float* out = (float*)d_out;

    dim3 grid(S_, H_, B_);
    tsattn_kernel<<<grid, 256, 0, stream>>>(q, k1, k2, v1, v2, out);
}

// Round 3
// 281.043 us; speedup vs baseline: 3.6348x; 3.6348x over previous
//
#include <hip/hip_runtime.h>
#include <math.h>

#define B_ 2
#define S_ 2048
#define H_ 4
#define D_ 64
#define W_ 64
#define ST 4                  // s-positions per block (1 per wave)
#define NR (W_ + ST)          // 68 staged window rows (block-relative r)
#define VSTR 104              // bf16 col stride: 208 B = 13 × 16B granules (odd → conflict-free)
#define SCALE_ 0.125f         // 1/sqrt(64)

typedef __attribute__((ext_vector_type(8))) short short8;   // 8 bf16 = 4 VGPR (MFMA A/B frag)
typedef __attribute__((ext_vector_type(4))) float f32x4;    // MFMA C/D frag

__device__ __forceinline__ unsigned short f2bf(float f) {   // RNE f32->bf16
    union { float f; unsigned u; } x; x.f = f;
    return (unsigned short)((x.u + 0x7FFFu + ((x.u >> 16) & 1u)) >> 16);
}

__global__ __launch_bounds__(256)
void tsattn_mfma(const float* __restrict__ q,
                 const float* __restrict__ k1,
                 const float* __restrict__ k2,
                 const float* __restrict__ v1,
                 const float* __restrict__ v2,
                 float* __restrict__ out)
{
    const int s0  = blockIdx.x * ST;
    const int h   = blockIdx.y;
    const int b   = blockIdx.z;
    const int tid = threadIdx.x;
    const int lane = tid & 63;
    const int w    = tid >> 6;      // wave id == s offset within block
    const int m16  = lane & 15;     // A row / B col / C-D col within 16-tile
    const int g4   = lane >> 4;     // k-group (A/B), row-group (C/D)

    // v2 transposed: v2T[d][r], r = block-relative window row. W strips per wave.
    __shared__ unsigned short v2T[D_][VSTR];
    __shared__ unsigned short Wst[ST][16][VSTR];

    const size_t base_bh = (size_t)(b * S_ * H_ + h) * D_;
#define ROW(j) (base_bh + (size_t)(j) * (H_ * D_))

    // ---- stage v2T (bf16) : zero pad cols [NR,VSTR) so 0-weight x garbage never makes NaN
    for (int idx = tid; idx < D_ * (VSTR - NR); idx += 256) {
        int d = idx / (VSTR - NR);
        int r = NR + idx % (VSTR - NR);
        v2T[d][r] = 0;
    }
    for (int idx = tid; idx < NR * (D_ / 4); idx += 256) {
        int r  = idx >> 4;
        int d4 = idx & 15;
        int j  = s0 - W_ + r; if (j < 0) j = 0;
        const float4 v = *(const float4*)(v2 + ROW(j) + 4 * d4);
        v2T[4 * d4 + 0][r] = f2bf(v.x);
        v2T[4 * d4 + 1][r] = f2bf(v.y);
        v2T[4 * d4 + 2][r] = f2bf(v.z);
        v2T[4 * d4 + 3][r] = f2bf(v.w);
    }
    __syncthreads();

    const int s    = s0 + w;
    const int amin = (s >= W_) ? 0 : (W_ - s);
    const size_t qoff = ROW(s);

    // q values this lane needs: qf[kk*8+j] = q[kk*32 + g4*8 + j]
    float qf[16];
    {
        const float* qp = q + qoff + g4 * 8;
        #pragma unroll
        for (int kk = 0; kk < 2; ++kk) {
            float4 x = *(const float4*)(qp + kk * 32);
            float4 y = *(const float4*)(qp + kk * 32 + 4);
            qf[kk*8+0]=x.x; qf[kk*8+1]=x.y; qf[kk*8+2]=x.z; qf[kk*8+3]=x.w;
            qf[kk*8+4]=y.x; qf[kk*8+5]=y.y; qf[kk*8+6]=y.z; qf[kk*8+7]=y.w;
        }
    }

    // B1 = K2^T fragments: B[k=d][n=c], lane holds col c = cm*16+m16, k = kk*32+g4*8+j
    short8 b1[5][2];
    #pragma unroll
    for (int cm = 0; cm < 5; ++cm) {
        int j = s - W_ + cm * 16 + m16;
        if (j < 0) j = 0; if (j > S_ - 1) j = S_ - 1;   // pad/garbage rows get masked at exp
        const float* kp = k2 + ROW(j) + g4 * 8;
        #pragma unroll
        for (int kk = 0; kk < 2; ++kk) {
            float4 x = *(const float4*)(kp + kk * 32);
            float4 y = *(const float4*)(kp + kk * 32 + 4);
            short8 f;
            f[0]=f2bf(x.x); f[1]=f2bf(x.y); f[2]=f2bf(x.z); f[3]=f2bf(x.w);
            f[4]=f2bf(y.x); f[5]=f2bf(y.y); f[6]=f2bf(y.z); f[7]=f2bf(y.w);
            b1[cm][kk] = f;
        }
    }

    // B2 = V2 fragments from v2T: B[k=r][n=d], lane holds d = dn*16+m16, r = kk*32+g4*8+j
    short8 b2[4][3];
    #pragma unroll
    for (int dn = 0; dn < 4; ++dn)
        #pragma unroll
        for (int kk = 0; kk < 3; ++kk)
            b2[dn][kk] = *(const short8*)&v2T[dn * 16 + m16][kk * 32 + g4 * 8];

    float dsum = 0.f;
    float pnum[4] = {0.f, 0.f, 0.f, 0.f};

    #pragma unroll
    for (int strip = 0; strip < 5; ++strip) {
        // A1 = P = q .* k1 : A[m=a][k=d], lane row a = strip*16+m16, k = kk*32+g4*8+j
        short8 a1[2];
        {
            int j = s - W_ + strip * 16 + m16;
            if (j < 0) j = 0; if (j > S_ - 1) j = S_ - 1;
            const float* kp = k1 + ROW(j) + g4 * 8;
            #pragma unroll
            for (int kk = 0; kk < 2; ++kk) {
                float4 x = *(const float4*)(kp + kk * 32);
                float4 y = *(const float4*)(kp + kk * 32 + 4);
                short8 f;
                f[0]=f2bf(x.x*qf[kk*8+0]); f[1]=f2bf(x.y*qf[kk*8+1]);
                f[2]=f2bf(x.z*qf[kk*8+2]); f[3]=f2bf(x.w*qf[kk*8+3]);
                f[4]=f2bf(y.x*qf[kk*8+4]); f[5]=f2bf(y.y*qf[kk*8+5]);
                f[6]=f2bf(y.z*qf[kk*8+6]); f[7]=f2bf(y.w*qf[kk*8+7]);
                a1[kk] = f;
            }
        }

        // scores for this 16-row strip vs all 5 c-tiles
        f32x4 acc1[5];
        #pragma unroll
        for (int cm = 0; cm < 5; ++cm) {
            acc1[cm] = (f32x4){0.f, 0.f, 0.f, 0.f};
            #pragma unroll
            for (int kk = 0; kk < 2; ++kk)
                acc1[cm] = __builtin_amdgcn_mfma_f32_16x16x32_bf16(a1[kk], b1[cm][kk], acc1[cm], 0, 0, 0);
        }

        // exp + mask; write W strip (cols shifted by w so phase-2 b128 reads stay aligned)
        #pragma unroll
        for (int cm = 0; cm < 5; ++cm) {
            const int c = cm * 16 + m16;
            #pragma unroll
            for (int r = 0; r < 4; ++r) {
                const int a = strip * 16 + g4 * 4 + r;
                const bool valid = (a >= amin) & (a <= W_) & (c >= amin) & (c <= W_);
                const float wv = valid ? __expf(acc1[cm][r] * SCALE_) : 0.f;
                dsum += wv;
                Wst[w][g4 * 4 + r][c + w] = f2bf(wv);
            }
        }
        // zero-fill K-pad cols [0,w) and [80+w,96)
        #pragma unroll
        for (int r = 0; r < 4; ++r) {
            if (m16 < w)           Wst[w][g4 * 4 + r][m16] = 0;
            if (80 + w + m16 < 96) Wst[w][g4 * 4 + r][80 + w + m16] = 0;
        }

        // phase 2: U[a][d] = sum_r W'[a][r] * v2blk[r][d], K = 96
        short8 a2[3];
        #pragma unroll
        for (int kk = 0; kk < 3; ++kk)
            a2[kk] = *(const short8*)&Wst[w][m16][kk * 32 + g4 * 8];

        #pragma unroll
        for (int dn = 0; dn < 4; ++dn) {
            f32x4 acc2 = (f32x4){0.f, 0.f, 0.f, 0.f};
            #pragma unroll
            for (int kk = 0; kk < 3; ++kk)
                acc2 = __builtin_amdgcn_mfma_f32_16x16x32_bf16(a2[kk], b2[dn][kk], acc2, 0, 0, 0);
            // num partial: U .* v1, reduce over a (regs now, lanes later)
            #pragma unroll
            for (int r = 0; r < 4; ++r) {
                const int a = strip * 16 + g4 * 4 + r;
                int j = s - W_ + a;
                if (j < 0) j = 0; if (j > S_ - 1) j = S_ - 1;   // a>64 rows: U==0, product 0
                pnum[dn] += acc2[r] * v1[ROW(j) + dn * 16 + m16];
            }
        }
    }

    // reductions: denom over all 64 lanes; num over the 4 row-groups
    #pragma unroll
    for (int off = 32; off >= 1; off >>= 1) dsum += __shfl_xor(dsum, off, 64);
    #pragma unroll
    for (int dn = 0; dn < 4; ++dn) {
        pnum[dn] += __shfl_xor(pnum[dn], 16, 64);
        pnum[dn] += __shfl_xor(pnum[dn], 32, 64);
    }
    if (lane < 16) {
        const float inv = 1.f / (dsum + 1e-8f);
        #pragma unroll
        for (int dn = 0; dn < 4; ++dn)
            out[qoff + dn * 16 + lane] = pnum[dn] * inv;
    }
#undef ROW
}

extern "C" void kernel_launch(void* const* d_in, const int* in_sizes, int n_in,
                              void* d_out, int out_size, void* d_ws, size_t ws_size,
                              hipStream_t stream) {
    const float* q  = (const float*)d_in[0];
    const float* k1 = (const float*)d_in[1];
    const float* k2 = (const float*)d_in[2];
    const float* v1 = (const float*)d_in[3];
    const float* v2 = (const float*)d_in[4];
    float* out = (float*)d_out;

    dim3 grid(S_ / ST, H_, B_);
    tsattn_mfma<<<grid, 256, 0, stream>>>(q, k1, k2, v1, v2, out);
}

// Round 4
// 219.280 us; speedup vs baseline: 4.6586x; 1.2817x over previous
//
#include <hip/hip_runtime.h>
#include <hip/hip_bf16.h>
#include <math.h>

#define B_ 2
#define S_ 2048
#define H_ 4
#define D_ 64
#define W_ 64
#define ST 4                  // s-positions per block (1 per wave)
#define VSTR 104              // bf16 col stride: 208 B = 13 × 16B granules (odd → conflict-free)
#define L2T 2144              // v2t row length: 64 zero-pad + 2048 + 32 zero-pad
#define EXPC 0.18033688011112042f   // SCALE * log2(e): exp(x*SCALE) = exp2(x*EXPC)

typedef __attribute__((ext_vector_type(8))) short short8;            // 8 bf16 = 4 VGPR
typedef __attribute__((ext_vector_type(4))) unsigned short ushort4_t; // 8B chunk
typedef __attribute__((ext_vector_type(4))) float f32x4;             // MFMA C/D frag

__device__ __forceinline__ unsigned short cbf(float f) {   // native RNE f32->bf16 (fuses to cvt_pk)
    __hip_bfloat16 h = __float2bfloat16(f);
    unsigned short u;
    __builtin_memcpy(&u, &h, 2);
    return u;
}

// ---- prologue 1: bulk f32 -> bf16 for k1, k2 (same layout) ----
__global__ __launch_bounds__(256)
void cvt2_kernel(const float* __restrict__ a, const float* __restrict__ b,
                 unsigned short* __restrict__ oa, unsigned short* __restrict__ ob, int n8) {
    int i = blockIdx.x * 256 + threadIdx.x;
    if (i >= 2 * n8) return;
    const float* s = (i < n8) ? a : b;
    unsigned short* d = (i < n8) ? oa : ob;
    int k = (i < n8) ? i : i - n8;
    float4 x = ((const float4*)s)[2 * k];
    float4 y = ((const float4*)s)[2 * k + 1];
    short8 o;
    o[0]=cbf(x.x); o[1]=cbf(x.y); o[2]=cbf(x.z); o[3]=cbf(x.w);
    o[4]=cbf(y.x); o[5]=cbf(y.y); o[6]=cbf(y.z); o[7]=cbf(y.w);
    *(short8*)(d + 8 * (size_t)k) = o;
}

// ---- prologue 2: v2 -> bf16 transposed [b][h][d][L2T], zero pads at both ends ----
__global__ __launch_bounds__(256)
void v2t_kernel(const float* __restrict__ v2, unsigned short* __restrict__ v2t) {
    const int s0 = blockIdx.x * 64;
    const int h = blockIdx.y, b = blockIdx.z;
    const int tid = threadIdx.x;
    __shared__ unsigned short t[64][72];
    const size_t base_bh = (size_t)(b * S_ * H_ + h) * D_;
    const int d = tid & 63;
    for (int i = tid >> 6; i < 64; i += 4)
        t[d][i] = cbf(v2[base_bh + (size_t)(s0 + i) * (H_ * D_) + d]);
    __syncthreads();
    const size_t obase = ((size_t)(b * H_ + h) * D_) * L2T;
    const short8 z = {0,0,0,0,0,0,0,0};
    for (int idx = tid; idx < 64 * 8; idx += 256) {
        int dd = idx >> 3, c8 = idx & 7;
        *(short8*)(v2t + obase + (size_t)dd * L2T + 64 + s0 + c8 * 8) = *(short8*)&t[dd][c8 * 8];
        if (blockIdx.x == 0)
            *(short8*)(v2t + obase + (size_t)dd * L2T + c8 * 8) = z;          // left pad [0,64)
    }
    if (blockIdx.x == (S_ / 64) - 1) {
        for (int idx = tid; idx < 64 * 4; idx += 256) {
            int dd = idx >> 2, c8 = idx & 3;
            *(short8*)(v2t + obase + (size_t)dd * L2T + 64 + S_ + c8 * 8) = z; // right pad [64+S,64+S+32)
        }
    }
}

// ---- main ----
__global__ __launch_bounds__(256, 3)
void tsattn_mfma(const float* __restrict__ q,
                 const unsigned short* __restrict__ k1b,
                 const unsigned short* __restrict__ k2b,
                 const float* __restrict__ v1,
                 const unsigned short* __restrict__ v2t,
                 float* __restrict__ out)
{
    const int s0  = blockIdx.x * ST;
    const int h   = blockIdx.y;
    const int b   = blockIdx.z;
    const int tid = threadIdx.x;
    const int lane = tid & 63;
    const int w    = tid >> 6;
    const int m16  = lane & 15;
    const int g4   = lane >> 4;

    __shared__ unsigned short v2T[D_][VSTR];        // block-relative window rows r=0..95
    __shared__ unsigned short Wst[ST][16][VSTR];

    const size_t base_bh = (size_t)(b * S_ * H_ + h) * D_;
#define ROW(j) (base_bh + (size_t)(j) * (H_ * D_))

    // stage v2T from preconverted/padded v2t: v2T[d][r] = v2[s0-W+r] (pads give zeros)
    {
        const unsigned short* src = v2t + ((size_t)(b * H_ + h) * D_) * L2T + s0; // col 64+(s0-W)+r = s0+r
        for (int idx = tid; idx < 64 * 24; idx += 256) {
            int d = idx / 24, rc = idx % 24;
            *(ushort4_t*)&v2T[d][rc * 4] = *(const ushort4_t*)(src + (size_t)d * L2T + rc * 4);
        }
    }
    __syncthreads();

    const int s    = s0 + w;
    const int amin = (s >= W_) ? 0 : (W_ - s);
    const size_t qoff = ROW(s);

    // q (f32) fragment values: qf[kk*8+j] = q[kk*32 + g4*8 + j]
    float qf[16];
    {
        const float* qp = q + qoff + g4 * 8;
        #pragma unroll
        for (int kk = 0; kk < 2; ++kk) {
            float4 x = *(const float4*)(qp + kk * 32);
            float4 y = *(const float4*)(qp + kk * 32 + 4);
            qf[kk*8+0]=x.x; qf[kk*8+1]=x.y; qf[kk*8+2]=x.z; qf[kk*8+3]=x.w;
            qf[kk*8+4]=y.x; qf[kk*8+5]=y.y; qf[kk*8+6]=y.z; qf[kk*8+7]=y.w;
        }
    }

    // B1 = K2^T fragments (direct bf16 loads): lane col c = cm*16+m16, k = kk*32+g4*8..+7
    short8 b1[5][2];
    #pragma unroll
    for (int cm = 0; cm < 5; ++cm) {
        int j = s - W_ + cm * 16 + m16;
        if (j < 0) j = 0; if (j > S_ - 1) j = S_ - 1;   // garbage rows masked at exp
        const unsigned short* kp = k2b + ROW(j) + g4 * 8;
        #pragma unroll
        for (int kk = 0; kk < 2; ++kk)
            b1[cm][kk] = *(const short8*)(kp + kk * 32);
    }

    // B2 = V2 fragments from v2T (block-relative r): lane d = dn*16+m16, r = kk*32+g4*8..+7
    short8 b2[4][3];
    #pragma unroll
    for (int dn = 0; dn < 4; ++dn)
        #pragma unroll
        for (int kk = 0; kk < 3; ++kk)
            b2[dn][kk] = *(const short8*)&v2T[dn * 16 + m16][kk * 32 + g4 * 8];

    // zero K-pad cols of this wave's W strip: [0,w) and [80+w,96)  (rows 16 via g4,r)
    #pragma unroll
    for (int r = 0; r < 4; ++r) {
        int row = g4 * 4 + r;
        if (m16 < w)      Wst[w][row][m16] = 0;
        if (m16 < 16 - w) Wst[w][row][80 + w + m16] = 0;
    }

    float dsum = 0.f;
    float pnum[4] = {0.f, 0.f, 0.f, 0.f};

    #pragma unroll
    for (int strip = 0; strip < 5; ++strip) {
        // A1 = P = q .* k1 (bf16 load, f32 mul, pack): lane row a = strip*16+m16
        short8 a1[2];
        {
            int j = s - W_ + strip * 16 + m16;
            if (j < 0) j = 0; if (j > S_ - 1) j = S_ - 1;
            const unsigned short* kp = k1b + ROW(j) + g4 * 8;
            #pragma unroll
            for (int kk = 0; kk < 2; ++kk) {
                short8 kv = *(const short8*)(kp + kk * 32);
                short8 f;
                #pragma unroll
                for (int j8 = 0; j8 < 8; ++j8) {
                    float kf = __uint_as_float(((unsigned)(unsigned short)kv[j8]) << 16);
                    f[j8] = (short)cbf(kf * qf[kk * 8 + j8]);
                }
                a1[kk] = f;
            }
        }

        f32x4 acc1[5];
        #pragma unroll
        for (int cm = 0; cm < 5; ++cm) {
            acc1[cm] = (f32x4){0.f, 0.f, 0.f, 0.f};
            #pragma unroll
            for (int kk = 0; kk < 2; ++kk)
                acc1[cm] = __builtin_amdgcn_mfma_f32_16x16x32_bf16(a1[kk], b1[cm][kk], acc1[cm], 0, 0, 0);
        }

        // exp + mask -> Wst (cols shifted by w so phase-2 reads stay 16B-aligned)
        #pragma unroll
        for (int cm = 0; cm < 5; ++cm) {
            const int c = cm * 16 + m16;
            const bool cok = (c >= amin) & (c <= W_);
            #pragma unroll
            for (int r = 0; r < 4; ++r) {
                const int a = strip * 16 + g4 * 4 + r;
                const bool valid = cok & (a >= amin) & (a <= W_);
                const float wv = valid ? exp2f(acc1[cm][r] * EXPC) : 0.f;
                dsum += wv;
                Wst[w][g4 * 4 + r][c + w] = cbf(wv);
            }
        }

        // phase 2: U[a][d] = sum_r W'[a][r] * v2T[r][d], K = 96
        short8 a2[3];
        #pragma unroll
        for (int kk = 0; kk < 3; ++kk)
            a2[kk] = *(const short8*)&Wst[w][m16][kk * 32 + g4 * 8];

        #pragma unroll
        for (int dn = 0; dn < 4; ++dn) {
            f32x4 acc2 = (f32x4){0.f, 0.f, 0.f, 0.f};
            #pragma unroll
            for (int kk = 0; kk < 3; ++kk)
                acc2 = __builtin_amdgcn_mfma_f32_16x16x32_bf16(a2[kk], b2[dn][kk], acc2, 0, 0, 0);
            #pragma unroll
            for (int r = 0; r < 4; ++r) {
                const int a = strip * 16 + g4 * 4 + r;
                int j = s - W_ + a;
                if (j < 0) j = 0; if (j > S_ - 1) j = S_ - 1;   // invalid rows: acc2==0
                pnum[dn] += acc2[r] * v1[ROW(j) + dn * 16 + m16];
            }
        }
    }

    #pragma unroll
    for (int off = 32; off >= 1; off >>= 1) dsum += __shfl_xor(dsum, off, 64);
    #pragma unroll
    for (int dn = 0; dn < 4; ++dn) {
        pnum[dn] += __shfl_xor(pnum[dn], 16, 64);
        pnum[dn] += __shfl_xor(pnum[dn], 32, 64);
    }
    if (lane < 16) {
        const float inv = 1.f / (dsum + 1e-8f);
        #pragma unroll
        for (int dn = 0; dn < 4; ++dn)
            out[qoff + dn * 16 + lane] = pnum[dn] * inv;
    }
#undef ROW
}

extern "C" void kernel_launch(void* const* d_in, const int* in_sizes, int n_in,
                              void* d_out, int out_size, void* d_ws, size_t ws_size,
                              hipStream_t stream) {
    const float* q  = (const float*)d_in[0];
    const float* k1 = (const float*)d_in[1];
    const float* k2 = (const float*)d_in[2];
    const float* v1 = (const float*)d_in[3];
    const float* v2 = (const float*)d_in[4];
    float* out = (float*)d_out;

    const size_t NE = (size_t)B_ * S_ * H_ * D_;   // 1,048,576 elements per tensor
    unsigned short* k1b = (unsigned short*)d_ws;
    unsigned short* k2b = k1b + NE;
    unsigned short* v2t = k2b + NE;                // B*H*D*L2T = 1,097,728 ushorts

    const int n8 = (int)(NE / 8);
    cvt2_kernel<<<(2 * n8 + 255) / 256, 256, 0, stream>>>(k1, k2, k1b, k2b, n8);
    v2t_kernel<<<dim3(S_ / 64, H_, B_), 256, 0, stream>>>(v2, v2t);

    dim3 grid(S_ / ST, H_, B_);
    tsattn_mfma<<<grid, 256, 0, stream>>>(q, k1b, k2b, v1, v2t, out);
}